// Round 12
// baseline (388.503 us; speedup 1.0000x reference)
//
#include <hip/hip_runtime.h>
#include <hip/hip_bf16.h>

#define N_NODES 50000
#define N_EDGES 1600000
#define DF 128
#define EPB 2500          // edges per partition block
#define B1 640            // partition blocks (EPB*B1 == N_EDGES)
#define NBIN 196          // ceil(50000/256)

typedef __attribute__((ext_vector_type(8))) short short8v;
typedef __attribute__((ext_vector_type(4))) float float4v;

__device__ __forceinline__ ushort bf16rne(float f) {
    uint u = __float_as_uint(f);
    return (ushort)((u + 0x7fffu + ((u >> 16) & 1u)) >> 16);
}

// ---------------- CSR build: two-level partition, no global atomics ----------------

__global__ __launch_bounds__(256) void h1_kernel(const int* __restrict__ dst,
                                                 int* __restrict__ gh) {
    __shared__ int hist[NBIN];
    const int tid = threadIdx.x;
    const int blk = blockIdx.x;
    if (tid < NBIN) hist[tid] = 0;
    __syncthreads();
    const int lo = blk * EPB, hiE = min(lo + EPB, N_EDGES);
    for (int i = lo + tid; i < hiE; i += 256) atomicAdd(&hist[dst[i] >> 8], 1);
    __syncthreads();
    if (tid < NBIN) gh[tid * B1 + blk] = hist[tid];
}

__global__ __launch_bounds__(256) void scanA_kernel(int* __restrict__ gh,
                                                    int* __restrict__ rowtot) {
    __shared__ int buf[256];
    __shared__ int carry_s;
    const int tid = threadIdx.x;
    const int d = blockIdx.x;
    if (tid == 0) carry_s = 0;
    __syncthreads();
    for (int base = 0; base < B1; base += 256) {
        int idx = base + tid;
        int v = (idx < B1) ? gh[d * B1 + idx] : 0;
        buf[tid] = v;
        __syncthreads();
#pragma unroll
        for (int off = 1; off < 256; off <<= 1) {
            int t = (tid >= off) ? buf[tid - off] : 0;
            __syncthreads();
            buf[tid] += t;
            __syncthreads();
        }
        int carry = carry_s;
        if (idx < B1) gh[d * B1 + idx] = carry + buf[tid] - v;
        int tot = buf[255];
        __syncthreads();
        if (tid == 0) carry_s = carry + tot;
        __syncthreads();
    }
    if (tid == 0) rowtot[d] = carry_s;
}

// also zeroes the bump-allocator counter (folds the memset dispatch)
__global__ __launch_bounds__(256) void scanB_kernel(const int* __restrict__ rowtot,
                                                    int* __restrict__ rowbase,
                                                    int* __restrict__ counter) {
    __shared__ int buf[256];
    const int tid = threadIdx.x;
    int v = (tid < NBIN) ? rowtot[tid] : 0;
    buf[tid] = v;
    __syncthreads();
#pragma unroll
    for (int off = 1; off < 256; off <<= 1) {
        int t = (tid >= off) ? buf[tid - off] : 0;
        __syncthreads();
        buf[tid] += t;
        __syncthreads();
    }
    if (tid < NBIN) rowbase[tid] = buf[tid] - v;
    if (tid == 0) {
        rowbase[NBIN] = buf[255];
        counter[0] = 0;
    }
}

__global__ __launch_bounds__(256) void scatter1_kernel(const int* __restrict__ src,
                                                       const int* __restrict__ dst,
                                                       const int* __restrict__ gh,
                                                       const int* __restrict__ rowbase,
                                                       uint2* __restrict__ tmp) {
    __shared__ int cur[NBIN];
    const int tid = threadIdx.x;
    const int blk = blockIdx.x;
    if (tid < NBIN) cur[tid] = rowbase[tid] + gh[tid * B1 + blk];
    __syncthreads();
    const int lo = blk * EPB, hiE = min(lo + EPB, N_EDGES);
    for (int i = lo + tid; i < hiE; i += 256) {
        int d = dst[i];
        int pos = atomicAdd(&cur[d >> 8], 1);
        uint2 v;
        v.x = (uint)src[i];
        v.y = (uint)d;
        tmp[pos] = v;
    }
}

__global__ __launch_bounds__(256) void pass2_kernel(const uint2* __restrict__ tmp,
                                                    const int* __restrict__ rowbase,
                                                    int* __restrict__ deg,
                                                    int* __restrict__ rstart,
                                                    int* __restrict__ adj,
                                                    int* __restrict__ counter) {
    __shared__ int hist[256];
    __shared__ int sbuf[256];
    __shared__ int cur2[256];
    __shared__ int base_s;
    const int tid = threadIdx.x;
    const int hi = blockIdx.x;
    const int s = rowbase[hi], e = rowbase[hi + 1];
    hist[tid] = 0;
    __syncthreads();
    for (int i = s + tid; i < e; i += 256) atomicAdd(&hist[tmp[i].y & 255u], 1);
    __syncthreads();
    int h = hist[tid];
    int v = (h + 3) & ~3;
    sbuf[tid] = v;
    __syncthreads();
#pragma unroll
    for (int off = 1; off < 256; off <<= 1) {
        int t = (tid >= off) ? sbuf[tid - off] : 0;
        __syncthreads();
        sbuf[tid] += t;
        __syncthreads();
    }
    if (tid == 255) base_s = atomicAdd(counter, sbuf[255]);
    __syncthreads();
    int rs = base_s + sbuf[tid] - v;
    int n = hi * 256 + tid;
    if (n < N_NODES) {
        deg[n] = h;
        rstart[n] = rs;
    }
    cur2[tid] = rs;
    __syncthreads();
    for (int i = s + tid; i < e; i += 256) {
        uint2 t2 = tmp[i];
        int pos = atomicAdd(&cur2[t2.y & 255u], 1);
        adj[pos] = (int)t2.x;
    }
}

// ---------------- prep: feats->bf16 conversion + all 3 layers' Wt (one dispatch) ---

#define CONV_TOT (N_NODES * DF / 4)          // 1.6M float4 elems
#define WPREP_TOT (3 * 128 * 256)            // 98304 elems

__global__ __launch_bounds__(256) void prep_kernel(const float* __restrict__ feats,
                                                   ushort* __restrict__ hb,
                                                   const float* __restrict__ wS0,
                                                   const float* __restrict__ wN0,
                                                   const float* __restrict__ wS1,
                                                   const float* __restrict__ wN1,
                                                   const float* __restrict__ wS2,
                                                   const float* __restrict__ wN2,
                                                   ushort* __restrict__ Wt) {
    int gid = blockIdx.x * 256 + threadIdx.x;
    if (gid < CONV_TOT) {
        float4 v = ((const float4*)feats)[gid];
        ushort4 o;
        o.x = bf16rne(v.x); o.y = bf16rne(v.y);
        o.z = bf16rne(v.z); o.w = bf16rne(v.w);
        ((ushort4*)hb)[gid] = o;
    } else {
        int j = gid - CONV_TOT;
        if (j < WPREP_TOT) {
            int l = j >> 15;              // layer 0..2
            int idx = j & 32767;
            int c = idx >> 8;
            int k = idx & 255;
            const float* wS = (l == 0) ? wS0 : (l == 1) ? wS1 : wS2;
            const float* wN = (l == 0) ? wN0 : (l == 1) ? wN1 : wN2;
            float v = (k < 128) ? wS[k * 128 + c] : wN[(k - 128) * 128 + c];
            Wt[(size_t)l * 128 * 256 + c * 256 + k] = bf16rne(v);
        }
    }
}

// ---------------- fused layer: agg (quarter-wave gather -> LDS) + MFMA GEMM -------
// Block = 64 nodes x 128 cols. Phase 1: 4 waves aggregate 16 nodes each into
// NT4[4][64][40] (MFMA-ready, 32-K chunks). Phase 2: GEMM; K-steps 0-3 stage
// self-features from global, K-steps 4-7 read A-frags from NT4.

template <bool RELU, bool FP32OUT>
__global__ __launch_bounds__(256, 2) void layer_kernel(const ushort* __restrict__ hbin,
                                                       const int* __restrict__ rstart,
                                                       const int* __restrict__ degv,
                                                       const int* __restrict__ adj,
                                                       const ushort* __restrict__ Wt,
                                                       const float* __restrict__ bias,
                                                       float* __restrict__ out32,
                                                       ushort* __restrict__ outbf) {
    __shared__ ushort NT4[4 * 64 * 40];   // neigh tile, 4 K-chunks x 64 rows x 32k(+8 pad)
    __shared__ ushort As[64 * 40];        // self-feature K-chunk staging
    __shared__ ushort Bs[128 * 40];       // weight panel
    const int tid = threadIdx.x;
    const int lane = tid & 63;
    const int w = tid >> 6;
    const int nbase = blockIdx.x * 64;
    const int q = lane >> 4;       // quarter
    const int f = lane & 15;       // 8-dim group
    const int l15 = lane & 15, l4 = lane >> 4;

    // ---------- phase 1: aggregate 16 nodes per wave ----------
    for (int t = 0; t < 16; ++t) {
        const int ln = w * 16 + t;
        const int n = nbase + ln;
        float acc[8];
#pragma unroll
        for (int j = 0; j < 8; j++) acc[j] = 0.f;
        int dd = 0;
        if (n < N_NODES) {
            const int s = rstart[n];
            dd = degv[n];
            const size_t foff = (size_t)(f * 8);
#define GATHER_ADD(EIDX)                                                    \
            {                                                               \
                int e_ = adj[(EIDX)];                                       \
                uint4 u_ = *(const uint4*)&hbin[(size_t)e_ * DF + foff];    \
                acc[0] += __uint_as_float(u_.x << 16);                      \
                acc[1] += __uint_as_float(u_.x & 0xffff0000u);              \
                acc[2] += __uint_as_float(u_.y << 16);                      \
                acc[3] += __uint_as_float(u_.y & 0xffff0000u);              \
                acc[4] += __uint_as_float(u_.z << 16);                      \
                acc[5] += __uint_as_float(u_.z & 0xffff0000u);              \
                acc[6] += __uint_as_float(u_.w << 16);                      \
                acc[7] += __uint_as_float(u_.w & 0xffff0000u);              \
            }
            int i = 0;
            for (; i + 16 <= dd; i += 16) {
                GATHER_ADD(s + i + q)
                GATHER_ADD(s + i + 4 + q)
                GATHER_ADD(s + i + 8 + q)
                GATHER_ADD(s + i + 12 + q)
            }
            for (; i + 4 <= dd; i += 4) {
                GATHER_ADD(s + i + q)
            }
            if (i < dd) {
                int r = dd - i;
                if (q < r) GATHER_ADD(s + i + q)
            }
#undef GATHER_ADD
        }
#pragma unroll
        for (int j = 0; j < 8; j++) {
            acc[j] += __shfl_xor(acc[j], 16, 64);
            acc[j] += __shfl_xor(acc[j], 32, 64);
        }
        if (q == 0) {
            float inv = 1.0f / (float)(dd < 1 ? 1 : dd);
            uint4 o;
            o.x = (uint)bf16rne(acc[0] * inv) | ((uint)bf16rne(acc[1] * inv) << 16);
            o.y = (uint)bf16rne(acc[2] * inv) | ((uint)bf16rne(acc[3] * inv) << 16);
            o.z = (uint)bf16rne(acc[4] * inv) | ((uint)bf16rne(acc[5] * inv) << 16);
            o.w = (uint)bf16rne(acc[6] * inv) | ((uint)bf16rne(acc[7] * inv) << 16);
            // chunk = f>>2, within-chunk 16B slot = f&3
            *(uint4*)&NT4[((f >> 2) * 64 + ln) * 40 + (f & 3) * 8] = o;
        }
    }
    __syncthreads();

    // ---------- phase 2: GEMM ----------
    float4v gacc[4][2];
#pragma unroll
    for (int i = 0; i < 4; i++)
#pragma unroll
        for (int j = 0; j < 2; j++) gacc[i][j] = (float4v)0.f;

    for (int ks = 0; ks < 8; ++ks) {
        const int k0 = ks * 32;
        if (ks) __syncthreads();
        if (ks < 4) {
            // stage self-features: 64 rows x 32 k = 256 x 16B chunks, 1/thread
            int r = tid >> 2, cp = tid & 3;
            int gn = nbase + r;
            if (gn > N_NODES - 1) gn = N_NODES - 1;
            *(uint4*)&As[r * 40 + cp * 8] =
                *(const uint4*)&hbin[(size_t)gn * 128 + k0 + cp * 8];
        }
        // stage B: 128 cols x 32 k = 512 chunks, 2/thread
#pragma unroll
        for (int j = 0; j < 2; j++) {
            int ch = tid + j * 256;
            int r = ch >> 2, cp = ch & 3;
            *(uint4*)&Bs[r * 40 + cp * 8] =
                *(const uint4*)&Wt[(size_t)r * 256 + k0 + cp * 8];
        }
        __syncthreads();
        const ushort* Atile = (ks < 4) ? As : &NT4[(ks - 4) * 64 * 40];
        short8v a[4], b[2];
#pragma unroll
        for (int i = 0; i < 4; i++)
            a[i] = *(const short8v*)&Atile[(i * 16 + l15) * 40 + l4 * 8];
#pragma unroll
        for (int j = 0; j < 2; j++)
            b[j] = *(const short8v*)&Bs[(w * 32 + j * 16 + l15) * 40 + l4 * 8];
#pragma unroll
        for (int i = 0; i < 4; i++)
#pragma unroll
            for (int j = 0; j < 2; j++)
                gacc[i][j] = __builtin_amdgcn_mfma_f32_16x16x32_bf16(
                    a[i], b[j], gacc[i][j], 0, 0, 0);
    }

    // ---------- epilogue ----------
#pragma unroll
    for (int j = 0; j < 2; j++) {
        int col = w * 32 + j * 16 + l15;
        float bv = bias[col];
#pragma unroll
        for (int i = 0; i < 4; i++) {
            int row0 = nbase + i * 16 + l4 * 4;
#pragma unroll
            for (int r = 0; r < 4; r++) {
                int row = row0 + r;
                if (row < N_NODES) {
                    float v = gacc[i][j][r] + bv;
                    if (RELU) v = fmaxf(v, 0.f);
                    if (FP32OUT) {
                        out32[(size_t)row * 128 + col] = v;
                    } else {
                        outbf[(size_t)row * 128 + col] = bf16rne(v);
                    }
                }
            }
        }
    }
}

// ---------------- launch ----------------

extern "C" void kernel_launch(void* const* d_in, const int* in_sizes, int n_in,
                              void* d_out, int out_size, void* d_ws, size_t ws_size,
                              hipStream_t stream) {
    const float* feats = (const float*)d_in[0];
    const int* src = (const int*)d_in[1];
    const int* dst = (const int*)d_in[2];
    const float* wS[3] = {(const float*)d_in[3], (const float*)d_in[6], (const float*)d_in[9]};
    const float* wN[3] = {(const float*)d_in[4], (const float*)d_in[7], (const float*)d_in[10]};
    const float* bb[3] = {(const float*)d_in[5], (const float*)d_in[8], (const float*)d_in[11]};
    float* out = (float*)d_out;

    char* p = (char*)d_ws;
    auto alloc = [&](size_t bytes) {
        char* r = p;
        p += (bytes + 255) & ~(size_t)255;
        return r;
    };
    ushort* hbA = (ushort*)alloc((size_t)N_NODES * DF * sizeof(ushort));    // 12.8 MB
    ushort* hbB = (ushort*)alloc((size_t)N_NODES * DF * sizeof(ushort));    // 12.8 MB
    ushort* Wt = (ushort*)alloc((size_t)3 * 128 * 256 * sizeof(ushort));    // 192 KB
    uint2* tmp = (uint2*)alloc((size_t)N_EDGES * sizeof(uint2));            // 12.8 MB
    int* gh = (int*)alloc((size_t)NBIN * B1 * sizeof(int));                 // 500 KB
    int* rowtot = (int*)alloc((size_t)NBIN * sizeof(int));
    int* rowbase = (int*)alloc((size_t)(NBIN + 1) * sizeof(int));
    int* deg = (int*)alloc((size_t)N_NODES * sizeof(int));
    int* rstart = (int*)alloc((size_t)N_NODES * sizeof(int));
    int* counter = (int*)alloc(sizeof(int));
    int* adj = (int*)alloc((size_t)(N_EDGES + 4 * N_NODES) * sizeof(int));  // 7.2 MB

    // CSR build via two-level partition (no global atomics in the hot path)
    h1_kernel<<<B1, 256, 0, stream>>>(dst, gh);
    scanA_kernel<<<NBIN, 256, 0, stream>>>(gh, rowtot);
    scanB_kernel<<<1, 256, 0, stream>>>(rowtot, rowbase, counter);
    scatter1_kernel<<<B1, 256, 0, stream>>>(src, dst, gh, rowbase, tmp);
    pass2_kernel<<<NBIN, 256, 0, stream>>>(tmp, rowbase, deg, rstart, adj, counter);

    // conversion + all weight prep in one dispatch
    const int PB = (CONV_TOT + WPREP_TOT + 255) / 256;
    prep_kernel<<<PB, 256, 0, stream>>>(feats, hbA, wS[0], wN[0], wS[1], wN[1],
                                        wS[2], wN[2], Wt);

    const int GB = (N_NODES + 63) / 64;

    // fused layers
    layer_kernel<true, false><<<GB, 256, 0, stream>>>(hbA, rstart, deg, adj,
                                                      Wt, bb[0], nullptr, hbB);
    layer_kernel<true, false><<<GB, 256, 0, stream>>>(hbB, rstart, deg, adj,
                                                      Wt + 128 * 256, bb[1], nullptr, hbA);
    layer_kernel<false, true><<<GB, 256, 0, stream>>>(hbA, rstart, deg, adj,
                                                      Wt + 2 * 128 * 256, bb[2], out, nullptr);
}